// Round 8
// baseline (165.935 us; speedup 1.0000x reference)
//
#include <hip/hip_runtime.h>
#include <hip/hip_bf16.h>

// out[i] = 10 * min_j ||x_i - y_j||, x: 8192x96 f32, y: 65536x96 f32.
// sq = x2[i] + (y2[j] - 2*x.y): bf16 MFMA computes (y2 - 2*x.y) by pre-scaling
// train by -2 (exact in bf16) and preloading y2 as the MFMA C operand.
// R8: pipe-balance fix. R6 (LDS ct=4) = LDS-bound (117c LDS vs 58c matrix /
// WG-tt); R7 (global ct=4) = TCP-bound (192c vs 58c). ct=8 doubles MFMA per
// staged byte: per WG-tile matrix 466c ~= LDS 477c ~= overlappable, TCP 192c.
// R2's ct=8 failed on spills: fixed w/ volatile bq, no dbuf regs, (256,3).
// Frag-major tbf (R7 prep): coalesced staging + conflict-free LDS (R6: 0).

typedef __attribute__((ext_vector_type(8))) short bf16x8;
typedef __attribute__((ext_vector_type(4))) float f32x4;

#define NQ 8192
#define NT 65536
#define KD 96
#define QB 512            // queries per WG: 4 waves x 128 (ct=8)
#define TSPLIT 128        // train chunks; grid = 16 * 128 = 2048
#define TCHUNK (NT / TSPLIT)   // 512 rows per WG
#define TTILE 64          // train rows per LDS tile
#define TILES (TCHUNK / TTILE) // 8
#define GRP_USH 1536      // ushorts per 16-row fragment group (3 kb x 64 x 8)

static __device__ __forceinline__ ushort f2bf(float f) {
  unsigned u = __float_as_uint(f);
  return (ushort)((u + 0x7fffu + ((u >> 16) & 1u)) >> 16);
}
static __device__ __forceinline__ unsigned pk2(float a, float b) {
  return (unsigned)f2bf(a) | ((unsigned)f2bf(b) << 16);
}

// Thread t owns float4s [6t, 6t+6) of its block's 64 rows = one quarter-row.
// Row norm = quad shuffle-reduce. Queries row-major; train FRAGMENT-MAJOR:
// ushort off = ((row>>4)*3 + kb)*512 + ((k>>3 & 3)*16 + (row&15))*8 + (k&7).
__global__ __launch_bounds__(256) void prep_kernel(
    const float* __restrict__ qf, const float* __restrict__ tf,
    ushort* __restrict__ qbf, ushort* __restrict__ tbf,
    float* __restrict__ x2, float* __restrict__ y2,
    float* __restrict__ outp)
{
  const int tid = threadIdx.x;
  const int b = blockIdx.x;
  const bool isq = b < (NQ / 64);
  const int rb = isq ? b : b - (NQ / 64);
  const int row = rb * 64 + (tid >> 2);
  const float4* src = (const float4*)((isq ? qf : tf) + (size_t)row * KD) + (tid & 3) * 6;
  const float scale = isq ? 1.0f : -2.0f;

  float s = 0.0f;
  #pragma unroll
  for (int i = 0; i < 6; ++i) {
    float4 v = src[i];
    s += v.x * v.x + v.y * v.y + v.z * v.z + v.w * v.w;
    uint2 p; p.x = pk2(v.x * scale, v.y * scale); p.y = pk2(v.z * scale, v.w * scale);
    int q4 = (tid & 3) * 6 + i;            // float4 index in row, 0..23
    if (isq) {
      *(uint2*)(qbf + (size_t)row * KD + q4 * 4) = p;
    } else {
      int kb = q4 >> 3, quad = (q4 >> 1) & 3, jh = q4 & 1;
      size_t off = ((size_t)(row >> 4) * 3 + kb) * 512 +
                   (quad * 16 + (row & 15)) * 8 + jh * 4;
      *(uint2*)(tbf + off) = p;
    }
  }
  s += __shfl_xor(s, 1, 64);
  s += __shfl_xor(s, 2, 64);
  if ((tid & 3) == 0) {
    if (isq) { x2[row] = s; outp[row] = __uint_as_float(0x7f800000u); }
    else     { y2[row] = s; }
  }
}

__global__ __launch_bounds__(256, 3) void min_dist_kernel(
    const ushort* __restrict__ qbf, const ushort* __restrict__ tbf,
    const float* __restrict__ x2, const float* __restrict__ y2,
    float* __restrict__ outp)
{
  __shared__ __align__(16) ushort ldsA[TTILE * KD];   // 12 KB, frag-major
  __shared__ __align__(16) float ldsY[TCHUNK];        // 2 KB, staged once

  const int tid  = threadIdx.x;
  const int w    = tid >> 6;
  const int lane = tid & 63;
  const int quad = lane >> 4;
  const int n    = lane & 15;
  const int tsplit = blockIdx.x & (TSPLIT - 1);
  const int qblock = blockIdx.x / TSPLIT;
  const int qbase  = qblock * QB + w * 128;
  const int trow0  = tsplit * TCHUNK;

  // stage this chunk's y2 (512 f32) into LDS
  *(float2*)&ldsY[tid * 2] = *(const float2*)(y2 + trow0 + tid * 2);

  // B-operand (query) fragments: 8 col-tiles x 3 k-blocks = 96 VGPRs.
  // volatile: forbid sinking these loads into the K-loop (R4/R5 pathology).
  bf16x8 bq[8][3];
  #pragma unroll
  for (int ct = 0; ct < 8; ++ct) {
    const ushort* qp = qbf + (size_t)(qbase + ct * 16 + n) * KD + quad * 8;
    #pragma unroll
    for (int kb = 0; kb < 3; ++kb)
      bq[ct][kb] = *(const volatile bf16x8*)(qp + kb * 32);
  }

  const float INF = __uint_as_float(0x7f800000u);
  float m[8];
  #pragma unroll
  for (int ct = 0; ct < 8; ++ct) m[ct] = INF;

  // frag-major global tile base: 64 rows = 12 KB contiguous
  const ushort* gbase = tbf + (size_t)(trow0 >> 4) * GRP_USH;

  #pragma unroll 1
  for (int tile = 0; tile < TILES; ++tile) {
    const ushort* g = gbase + (size_t)tile * (TTILE / 16) * GRP_USH;
    __syncthreads();   // previous compute done (also publishes ldsY 1st time)
    #pragma unroll
    for (int it = 0; it < 3; ++it) {
      int c = it * 256 + tid;                    // 16B chunk id, 0..767
      *(uint4*)&ldsA[c * 8] = *(const uint4*)(g + c * 8);
    }
    __syncthreads();

    #pragma unroll
    for (int tt = 0; tt < 4; ++tt) {
      const ushort* ap = &ldsA[tt * 3 * 512 + lane * 8];
      bf16x8 a0 = *(const bf16x8*)(ap);
      bf16x8 a1 = *(const bf16x8*)(ap + 512);
      bf16x8 a2 = *(const bf16x8*)(ap + 1024);
      f32x4 y2v = *(const f32x4*)&ldsY[tile * TTILE + tt * 16 + quad * 4];
      #pragma unroll
      for (int ct = 0; ct < 8; ++ct) {
        f32x4 acc = __builtin_amdgcn_mfma_f32_16x16x32_bf16(a0, bq[ct][0], y2v, 0, 0, 0);
        acc = __builtin_amdgcn_mfma_f32_16x16x32_bf16(a1, bq[ct][1], acc, 0, 0, 0);
        acc = __builtin_amdgcn_mfma_f32_16x16x32_bf16(a2, bq[ct][2], acc, 0, 0, 0);
        m[ct] = fminf(fminf(fminf(acc[0], acc[1]), acc[2]), fminf(acc[3], m[ct]));
      }
    }
  }

  // fold across quads (lanes with equal n hold the same query columns)
  #pragma unroll
  for (int ct = 0; ct < 8; ++ct) {
    m[ct] = fminf(m[ct], __shfl_xor(m[ct], 16, 64));
    m[ct] = fminf(m[ct], __shfl_xor(m[ct], 32, 64));
  }
  if (quad == 0) {
    #pragma unroll
    for (int ct = 0; ct < 8; ++ct) {
      int q = qbase + ct * 16 + n;
      float sq = fmaxf(x2[q] + m[ct], 0.0f);
      float val = sqrtf(sq) * 10.0f;
      atomicMin((unsigned int*)&outp[q], __float_as_uint(val));
    }
  }
}

extern "C" void kernel_launch(void* const* d_in, const int* in_sizes, int n_in,
                              void* d_out, int out_size, void* d_ws, size_t ws_size,
                              hipStream_t stream) {
  const float* qf = (const float*)d_in[0];   // mutation_dist 8192x96
  const float* tf = (const float*)d_in[1];   // train_data   65536x96
  float* outp = (float*)d_out;               // 8192 f32

  ushort* qbf = (ushort*)d_ws;                // 8192*96 bf16, row-major
  ushort* tbf = qbf + (size_t)NQ * KD;        // 65536*96 bf16, frag-major, -2x
  float* x2 = (float*)(tbf + (size_t)NT * KD);
  float* y2 = x2 + NQ;

  prep_kernel<<<(NQ + NT) / 64, 256, 0, stream>>>(qf, tf, qbf, tbf, x2, y2, outp);
  min_dist_kernel<<<(NQ / QB) * TSPLIT, 256, 0, stream>>>(qbf, tbf, x2, y2, outp);
}

// Round 9
// 163.394 us; speedup vs baseline: 1.0156x; 1.0156x over previous
//
#include <hip/hip_runtime.h>
#include <hip/hip_bf16.h>

// out[i] = 10 * min_j ||x_i - y_j||, x: 8192x96 f32, y: 65536x96 f32.
// sq = x2[i] + (y2[j] - 2*x.y): bf16 MFMA computes (y2 - 2*x.y) by pre-scaling
// train by -2 (exact in bf16) and preloading y2 as the MFMA C operand.
// R9: occupancy is VGPR-bucketed (waves/SIMD = 8/4/2 at real vgpr 64/128/256;
// CSV VGPR_Count ~ real/2 -- fits R4/R5/R7/R8 occupancy 4-for-4). ct=8 (R8)
// = 152 real regs = 2-wave bucket = latency-bound. R9 threads the needle:
// ct=6 (96 queries/wave, NQ padded to 8448), bq=72 regs, est ~116 real ->
// 4-wave bucket; distribution split across BOTH pipes: kb0/kb1 via LDS
// (8KB rd + 2KB wr per WG-tt), kb2 per-wave from global w/ prefetch (TCP).
// Per-CU round: matrix 349c >= LDS 312c ~= TCP 312c -> matrix-bound.

typedef __attribute__((ext_vector_type(8))) short bf16x8;
typedef __attribute__((ext_vector_type(4))) float f32x4;

#define NQ 8192
#define NQP 8448          // padded to 22 * 384
#define NT 65536
#define KD 96
#define QB 384            // queries per WG: 4 waves x 96 (ct=6)
#define TSPLIT 128        // train chunks; same tsplit => same XCD (128%8==0)
#define TCHUNK (NT / TSPLIT)   // 512 rows per WG
#define TILE 128          // train rows per LDS stage (kb0/kb1 only: 16 KB)
#define NTILES (TCHUNK / TILE) // 4
#define GRP_USH 1536      // ushorts per 16-row fragment group (3 kb x 64 x 8)

static __device__ __forceinline__ ushort f2bf(float f) {
  unsigned u = __float_as_uint(f);
  return (ushort)((u + 0x7fffu + ((u >> 16) & 1u)) >> 16);
}
static __device__ __forceinline__ unsigned pk2(float a, float b) {
  return (unsigned)f2bf(a) | ((unsigned)f2bf(b) << 16);
}

// Thread t owns float4s [6t, 6t+6) of its block's 64 rows = one quarter-row.
// Row norm = quad shuffle-reduce. Queries row-major (rows >= NQ zero-padded);
// train FRAGMENT-MAJOR: off = ((row>>4)*3 + kb)*512 + (quad*16+(row&15))*8+j.
__global__ __launch_bounds__(256) void prep_kernel(
    const float* __restrict__ qf, const float* __restrict__ tf,
    ushort* __restrict__ qbf, ushort* __restrict__ tbf,
    float* __restrict__ x2, float* __restrict__ y2,
    float* __restrict__ outp)
{
  const int tid = threadIdx.x;
  const int b = blockIdx.x;
  const bool isq = b < (NQP / 64);
  const int rb = isq ? b : b - (NQP / 64);
  const int row = rb * 64 + (tid >> 2);
  const bool pad = isq && (row >= NQ);
  const float4* src = (const float4*)((isq ? qf : tf) + (size_t)row * KD) + (tid & 3) * 6;
  const float scale = isq ? 1.0f : -2.0f;

  float s = 0.0f;
  #pragma unroll
  for (int i = 0; i < 6; ++i) {
    float4 v = pad ? make_float4(0.f, 0.f, 0.f, 0.f) : src[i];
    s += v.x * v.x + v.y * v.y + v.z * v.z + v.w * v.w;
    uint2 p; p.x = pk2(v.x * scale, v.y * scale); p.y = pk2(v.z * scale, v.w * scale);
    int q4 = (tid & 3) * 6 + i;            // float4 index in row, 0..23
    if (isq) {
      *(uint2*)(qbf + (size_t)row * KD + q4 * 4) = p;
    } else {
      int kb = q4 >> 3, quad = (q4 >> 1) & 3, jh = q4 & 1;
      size_t off = ((size_t)(row >> 4) * 3 + kb) * 512 +
                   (quad * 16 + (row & 15)) * 8 + jh * 4;
      *(uint2*)(tbf + off) = p;
    }
  }
  s += __shfl_xor(s, 1, 64);
  s += __shfl_xor(s, 2, 64);
  if ((tid & 3) == 0 && !pad) {
    if (isq) { x2[row] = s; outp[row] = __uint_as_float(0x7f800000u); }
    else     { y2[row] = s; }
  }
}

__global__ __launch_bounds__(256, 4) void min_dist_kernel(
    const ushort* __restrict__ qbf, const ushort* __restrict__ tbf,
    const float* __restrict__ x2, const float* __restrict__ y2,
    float* __restrict__ outp)
{
  // kb0/kb1 fragment blocks for a 128-row tile: [8 grp][2 kb][512]
  __shared__ __align__(16) ushort ldsA[TILE / 16 * 2 * 512];  // 16 KB
  __shared__ __align__(16) float ldsY[TCHUNK];                // 2 KB

  const int tid  = threadIdx.x;
  const int w    = tid >> 6;
  const int lane = tid & 63;
  const int quad = lane >> 4;
  const int n    = lane & 15;
  const int tsplit = blockIdx.x & (TSPLIT - 1);
  const int qblock = blockIdx.x / TSPLIT;
  const int qbase  = qblock * QB + w * 96;
  const int trow0  = tsplit * TCHUNK;

  // stage this chunk's y2 (512 f32) into LDS
  *(float2*)&ldsY[tid * 2] = *(const float2*)(y2 + trow0 + tid * 2);

  // B-operand (query) fragments: 6 col-tiles x 3 kb = 72 VGPRs, resident.
  // volatile: forbid sinking into the K-loop (R5 pathology).
  bf16x8 bq[6][3];
  #pragma unroll
  for (int ct = 0; ct < 6; ++ct) {
    const ushort* qp = qbf + (size_t)(qbase + ct * 16 + n) * KD + quad * 8;
    #pragma unroll
    for (int kb = 0; kb < 3; ++kb)
      bq[ct][kb] = *(const volatile bf16x8*)(qp + kb * 32);
  }

  const float INF = __uint_as_float(0x7f800000u);
  float m0 = INF, m1 = INF, m2 = INF, m3 = INF, m4 = INF, m5 = INF;

  // kb2 stream: per-wave from global, frag-major, one-grp-ahead prefetch.
  // (final prefetch over-reads one grp -> lands in x2/y2 region: in-ws, unused)
  const ushort* pa2 = tbf + (size_t)(trow0 >> 4) * GRP_USH + 1024 + lane * 8;
  bf16x8 a2c = *(const bf16x8*)pa2;
  pa2 += GRP_USH;

  #pragma unroll 1
  for (int tile = 0; tile < NTILES; ++tile) {
    const ushort* g = tbf + (size_t)((trow0 >> 4) + tile * (TILE / 16)) * GRP_USH;
    __syncthreads();
    // stage kb0/kb1 of 128 rows: 16 KB; chunk c (16B): frag=c>>6 (grp*2+kb)
    #pragma unroll
    for (int it = 0; it < 4; ++it) {
      int c = it * 256 + tid;                        // 0..1023
      int frag = c >> 6, l = c & 63;
      int grp_l = frag >> 1, kb = frag & 1;
      *(uint4*)&ldsA[c * 8] =
          *(const uint4*)(g + ((size_t)grp_l * 3 + kb) * 512 + l * 8);
    }
    __syncthreads();

    #pragma unroll
    for (int tt = 0; tt < TILE / 16; ++tt) {
      bf16x8 a2n = *(const bf16x8*)pa2;   // prefetch next grp's kb2
      pa2 += GRP_USH;
      const ushort* ap = &ldsA[tt * 1024 + lane * 8];
      bf16x8 a0 = *(const bf16x8*)(ap);
      bf16x8 a1 = *(const bf16x8*)(ap + 512);
      f32x4 y2v = *(const f32x4*)&ldsY[tile * TILE + tt * 16 + quad * 4];

      f32x4 acc;
      acc = __builtin_amdgcn_mfma_f32_16x16x32_bf16(a0, bq[0][0], y2v, 0, 0, 0);
      acc = __builtin_amdgcn_mfma_f32_16x16x32_bf16(a1, bq[0][1], acc, 0, 0, 0);
      acc = __builtin_amdgcn_mfma_f32_16x16x32_bf16(a2c, bq[0][2], acc, 0, 0, 0);
      m0 = fminf(fminf(fminf(acc[0], acc[1]), acc[2]), fminf(acc[3], m0));

      acc = __builtin_amdgcn_mfma_f32_16x16x32_bf16(a0, bq[1][0], y2v, 0, 0, 0);
      acc = __builtin_amdgcn_mfma_f32_16x16x32_bf16(a1, bq[1][1], acc, 0, 0, 0);
      acc = __builtin_amdgcn_mfma_f32_16x16x32_bf16(a2c, bq[1][2], acc, 0, 0, 0);
      m1 = fminf(fminf(fminf(acc[0], acc[1]), acc[2]), fminf(acc[3], m1));

      acc = __builtin_amdgcn_mfma_f32_16x16x32_bf16(a0, bq[2][0], y2v, 0, 0, 0);
      acc = __builtin_amdgcn_mfma_f32_16x16x32_bf16(a1, bq[2][1], acc, 0, 0, 0);
      acc = __builtin_amdgcn_mfma_f32_16x16x32_bf16(a2c, bq[2][2], acc, 0, 0, 0);
      m2 = fminf(fminf(fminf(acc[0], acc[1]), acc[2]), fminf(acc[3], m2));

      acc = __builtin_amdgcn_mfma_f32_16x16x32_bf16(a0, bq[3][0], y2v, 0, 0, 0);
      acc = __builtin_amdgcn_mfma_f32_16x16x32_bf16(a1, bq[3][1], acc, 0, 0, 0);
      acc = __builtin_amdgcn_mfma_f32_16x16x32_bf16(a2c, bq[3][2], acc, 0, 0, 0);
      m3 = fminf(fminf(fminf(acc[0], acc[1]), acc[2]), fminf(acc[3], m3));

      acc = __builtin_amdgcn_mfma_f32_16x16x32_bf16(a0, bq[4][0], y2v, 0, 0, 0);
      acc = __builtin_amdgcn_mfma_f32_16x16x32_bf16(a1, bq[4][1], acc, 0, 0, 0);
      acc = __builtin_amdgcn_mfma_f32_16x16x32_bf16(a2c, bq[4][2], acc, 0, 0, 0);
      m4 = fminf(fminf(fminf(acc[0], acc[1]), acc[2]), fminf(acc[3], m4));

      acc = __builtin_amdgcn_mfma_f32_16x16x32_bf16(a0, bq[5][0], y2v, 0, 0, 0);
      acc = __builtin_amdgcn_mfma_f32_16x16x32_bf16(a1, bq[5][1], acc, 0, 0, 0);
      acc = __builtin_amdgcn_mfma_f32_16x16x32_bf16(a2c, bq[5][2], acc, 0, 0, 0);
      m5 = fminf(fminf(fminf(acc[0], acc[1]), acc[2]), fminf(acc[3], m5));

      a2c = a2n;
    }
  }

  // fold across quads (lanes with equal n hold the same query columns)
  float m[6] = {m0, m1, m2, m3, m4, m5};
  #pragma unroll
  for (int ct = 0; ct < 6; ++ct) {
    m[ct] = fminf(m[ct], __shfl_xor(m[ct], 16, 64));
    m[ct] = fminf(m[ct], __shfl_xor(m[ct], 32, 64));
  }
  if (quad == 0) {
    #pragma unroll
    for (int ct = 0; ct < 6; ++ct) {
      int q = qbase + ct * 16 + n;
      if (q < NQ) {
        float sq = fmaxf(x2[q] + m[ct], 0.0f);
        float val = sqrtf(sq) * 10.0f;
        atomicMin((unsigned int*)&outp[q], __float_as_uint(val));
      }
    }
  }
}

extern "C" void kernel_launch(void* const* d_in, const int* in_sizes, int n_in,
                              void* d_out, int out_size, void* d_ws, size_t ws_size,
                              hipStream_t stream) {
  const float* qf = (const float*)d_in[0];   // mutation_dist 8192x96
  const float* tf = (const float*)d_in[1];   // train_data   65536x96
  float* outp = (float*)d_out;               // 8192 f32

  ushort* qbf = (ushort*)d_ws;                // 8448*96 bf16, row-major (padded)
  ushort* tbf = qbf + (size_t)NQP * KD;       // 65536*96 bf16, frag-major, -2x
  float* x2 = (float*)(tbf + (size_t)NT * KD);
  float* y2 = x2 + NQ;

  prep_kernel<<<(NQP + NT) / 64, 256, 0, stream>>>(qf, tf, qbf, tbf, x2, y2, outp);
  min_dist_kernel<<<(NQP / QB) * TSPLIT, 256, 0, stream>>>(qbf, tbf, x2, y2, outp);
}

// Round 10
// 155.550 us; speedup vs baseline: 1.0668x; 1.0504x over previous
//
#include <hip/hip_runtime.h>
#include <hip/hip_bf16.h>

// out[i] = 10 * min_j ||x_i - y_j||, x: 8192x96 f32, y: 65536x96 f32.
// sq = x2[i] + (y2[j] - 2*x.y): bf16 MFMA computes (y2 - 2*x.y) by pre-scaling
// train by -2 (exact in bf16) and preloading y2 as the MFMA C operand.
// R10: R6 skeleton (84us = 61% of the 51us matrix floor) + m97-style async
// global_load_lds(16B) double-buffer, ONE barrier per tile. DMA for tile t+1
// issues right after the barrier releasing tile t's compute; the pre-barrier
// vmcnt(0) drain lands after 931 CU-cyc of MFMA -> staging latency hidden.
// Frag-major tbf (prep) makes the tile a contiguous 12KB block whose chunks
// are exactly wave-uniform-base + lane*16 (the DMA's required layout).

typedef __attribute__((ext_vector_type(8))) short bf16x8;
typedef __attribute__((ext_vector_type(4))) float f32x4;

#define NQ 8192
#define NT 65536
#define KD 96
#define QB 256            // queries per WG: 4 waves x 64 (ct=4)
#define TSPLIT 64         // train chunks; chunk t -> XCD t%8
#define TCHUNK (NT / TSPLIT)   // 1024 rows per WG
#define TTILE 64          // train rows per LDS tile
#define TILES (TCHUNK / TTILE) // 16
#define GRP_USH 1536      // ushorts per 16-row fragment group (3 kb x 64 x 8)

static __device__ __forceinline__ ushort f2bf(float f) {
  unsigned u = __float_as_uint(f);
  return (ushort)((u + 0x7fffu + ((u >> 16) & 1u)) >> 16);
}
static __device__ __forceinline__ unsigned pk2(float a, float b) {
  return (unsigned)f2bf(a) | ((unsigned)f2bf(b) << 16);
}
static __device__ __forceinline__ void async_copy16(const ushort* g, ushort* l) {
  __builtin_amdgcn_global_load_lds(
      (const __attribute__((address_space(1))) void*)g,
      (__attribute__((address_space(3))) void*)l, 16, 0, 0);
}

// Thread t owns float4s [6t, 6t+6) of its block's 64 rows = one quarter-row.
// Row norm = quad shuffle-reduce. Queries row-major; train FRAGMENT-MAJOR:
// off = ((row>>4)*3 + kb)*512 + (quad*16 + (row&15))*8 + j.
__global__ __launch_bounds__(256) void prep_kernel(
    const float* __restrict__ qf, const float* __restrict__ tf,
    ushort* __restrict__ qbf, ushort* __restrict__ tbf,
    float* __restrict__ x2, float* __restrict__ y2,
    float* __restrict__ outp)
{
  const int tid = threadIdx.x;
  const int b = blockIdx.x;
  const bool isq = b < (NQ / 64);
  const int rb = isq ? b : b - (NQ / 64);
  const int row = rb * 64 + (tid >> 2);
  const float4* src = (const float4*)((isq ? qf : tf) + (size_t)row * KD) + (tid & 3) * 6;
  const float scale = isq ? 1.0f : -2.0f;

  float s = 0.0f;
  #pragma unroll
  for (int i = 0; i < 6; ++i) {
    float4 v = src[i];
    s += v.x * v.x + v.y * v.y + v.z * v.z + v.w * v.w;
    uint2 p; p.x = pk2(v.x * scale, v.y * scale); p.y = pk2(v.z * scale, v.w * scale);
    int q4 = (tid & 3) * 6 + i;            // float4 index in row, 0..23
    if (isq) {
      *(uint2*)(qbf + (size_t)row * KD + q4 * 4) = p;
    } else {
      int kb = q4 >> 3, quad = (q4 >> 1) & 3, jh = q4 & 1;
      size_t off = ((size_t)(row >> 4) * 3 + kb) * 512 +
                   (quad * 16 + (row & 15)) * 8 + jh * 4;
      *(uint2*)(tbf + off) = p;
    }
  }
  s += __shfl_xor(s, 1, 64);
  s += __shfl_xor(s, 2, 64);
  if ((tid & 3) == 0) {
    if (isq) { x2[row] = s; outp[row] = __uint_as_float(0x7f800000u); }
    else     { y2[row] = s; }
  }
}

__global__ __launch_bounds__(256, 4) void min_dist_kernel(
    const ushort* __restrict__ qbf, const ushort* __restrict__ tbf,
    const float* __restrict__ x2, const float* __restrict__ y2,
    float* __restrict__ outp)
{
  __shared__ __align__(16) ushort ldsA[2][TTILE * KD];  // 2 x 12 KB, frag-major
  __shared__ __align__(16) float ldsY[TCHUNK];          // 4 KB

  const int tid  = threadIdx.x;
  const int w    = tid >> 6;
  const int lane = tid & 63;
  const int quad = lane >> 4;
  const int n    = lane & 15;
  const int tsplit = blockIdx.x & (TSPLIT - 1);   // -> XCD tsplit%8
  const int qblock = blockIdx.x / TSPLIT;
  const int qbase  = qblock * QB + w * 64;
  const int trow0  = tsplit * TCHUNK;

  // frag-major chunk base for this WG's train rows
  const ushort* gbase = tbf + (size_t)(trow0 >> 4) * GRP_USH;

  // prologue: async-stage tile 0 into buf 0; stage y2 chunk (1024 f32)
  #pragma unroll
  for (int it = 0; it < 3; ++it) {
    int c = it * 256 + tid;                 // 16B chunk id 0..767
    async_copy16(gbase + c * 8, &ldsA[0][c * 8]);
  }
  *(float4*)&ldsY[tid * 4] = *(const float4*)(y2 + trow0 + tid * 4);

  // B-operand (query) fragments: 4 col-tiles x 3 kb = 48 VGPRs, resident.
  // volatile: forbid sinking into the K-loop (R5 pathology).
  bf16x8 bq[4][3];
  #pragma unroll
  for (int ct = 0; ct < 4; ++ct) {
    const ushort* qp = qbf + (size_t)(qbase + ct * 16 + n) * KD + quad * 8;
    #pragma unroll
    for (int kb = 0; kb < 3; ++kb)
      bq[ct][kb] = *(const volatile bf16x8*)(qp + kb * 32);
  }

  const float INF = __uint_as_float(0x7f800000u);
  float m0 = INF, m1 = INF, m2 = INF, m3 = INF;

  __syncthreads();   // tile0 DMA + ldsY drained (vmcnt(0) before barrier)

  int cur = 0;
  #pragma unroll 1
  for (int tile = 0; tile < TILES; ++tile) {
    if (tile + 1 < TILES) {
      const ushort* g = gbase + (size_t)(tile + 1) * (TTILE / 16) * GRP_USH;
      #pragma unroll
      for (int it = 0; it < 3; ++it) {
        int c = it * 256 + tid;
        async_copy16(g + c * 8, &ldsA[cur ^ 1][c * 8]);
      }
    }

    #pragma unroll
    for (int tt = 0; tt < 4; ++tt) {
      const ushort* ap = &ldsA[cur][tt * 3 * 512 + lane * 8];
      bf16x8 a0 = *(const bf16x8*)(ap);
      bf16x8 a1 = *(const bf16x8*)(ap + 512);
      bf16x8 a2 = *(const bf16x8*)(ap + 1024);
      f32x4 y2v = *(const f32x4*)&ldsY[tile * TTILE + tt * 16 + quad * 4];

      f32x4 acc;
      acc = __builtin_amdgcn_mfma_f32_16x16x32_bf16(a0, bq[0][0], y2v, 0, 0, 0);
      acc = __builtin_amdgcn_mfma_f32_16x16x32_bf16(a1, bq[0][1], acc, 0, 0, 0);
      acc = __builtin_amdgcn_mfma_f32_16x16x32_bf16(a2, bq[0][2], acc, 0, 0, 0);
      m0 = fminf(fminf(fminf(acc[0], acc[1]), acc[2]), fminf(acc[3], m0));

      acc = __builtin_amdgcn_mfma_f32_16x16x32_bf16(a0, bq[1][0], y2v, 0, 0, 0);
      acc = __builtin_amdgcn_mfma_f32_16x16x32_bf16(a1, bq[1][1], acc, 0, 0, 0);
      acc = __builtin_amdgcn_mfma_f32_16x16x32_bf16(a2, bq[1][2], acc, 0, 0, 0);
      m1 = fminf(fminf(fminf(acc[0], acc[1]), acc[2]), fminf(acc[3], m1));

      acc = __builtin_amdgcn_mfma_f32_16x16x32_bf16(a0, bq[2][0], y2v, 0, 0, 0);
      acc = __builtin_amdgcn_mfma_f32_16x16x32_bf16(a1, bq[2][1], acc, 0, 0, 0);
      acc = __builtin_amdgcn_mfma_f32_16x16x32_bf16(a2, bq[2][2], acc, 0, 0, 0);
      m2 = fminf(fminf(fminf(acc[0], acc[1]), acc[2]), fminf(acc[3], m2));

      acc = __builtin_amdgcn_mfma_f32_16x16x32_bf16(a0, bq[3][0], y2v, 0, 0, 0);
      acc = __builtin_amdgcn_mfma_f32_16x16x32_bf16(a1, bq[3][1], acc, 0, 0, 0);
      acc = __builtin_amdgcn_mfma_f32_16x16x32_bf16(a2, bq[3][2], acc, 0, 0, 0);
      m3 = fminf(fminf(fminf(acc[0], acc[1]), acc[2]), fminf(acc[3], m3));
    }

    __syncthreads();   // drains next tile's DMA; releases buf for rewrite
    cur ^= 1;
  }

  // fold across quads (lanes with equal n hold the same query columns)
  float m[4] = {m0, m1, m2, m3};
  #pragma unroll
  for (int ct = 0; ct < 4; ++ct) {
    m[ct] = fminf(m[ct], __shfl_xor(m[ct], 16, 64));
    m[ct] = fminf(m[ct], __shfl_xor(m[ct], 32, 64));
  }
  if (quad == 0) {
    #pragma unroll
    for (int ct = 0; ct < 4; ++ct) {
      int q = qbase + ct * 16 + n;
      float sq = fmaxf(x2[q] + m[ct], 0.0f);
      float val = sqrtf(sq) * 10.0f;
      atomicMin((unsigned int*)&outp[q], __float_as_uint(val));
    }
  }
}

extern "C" void kernel_launch(void* const* d_in, const int* in_sizes, int n_in,
                              void* d_out, int out_size, void* d_ws, size_t ws_size,
                              hipStream_t stream) {
  const float* qf = (const float*)d_in[0];   // mutation_dist 8192x96
  const float* tf = (const float*)d_in[1];   // train_data   65536x96
  float* outp = (float*)d_out;               // 8192 f32

  ushort* qbf = (ushort*)d_ws;                // 8192*96 bf16, row-major
  ushort* tbf = qbf + (size_t)NQ * KD;        // 65536*96 bf16, frag-major, -2x
  float* x2 = (float*)(tbf + (size_t)NT * KD);
  float* y2 = x2 + NQ;

  prep_kernel<<<(NQ + NT) / 64, 256, 0, stream>>>(qf, tf, qbf, tbf, x2, y2, outp);
  min_dist_kernel<<<(NQ / QB) * TSPLIT, 256, 0, stream>>>(qbf, tbf, x2, y2, outp);
}